// Round 10
// baseline (114.319 us; speedup 1.0000x reference)
//
#include <hip/hip_runtime.h>
#include <math.h>
#include <float.h>

// Problem constants (from reference)
#define NPT     16384
#define IN_F    34
#define SDIM    4
#define PDIM    22
#define KNN     8
#define WIDTH   126
#define WPAD    128    // padded width for conflict-free LDS
#define NCLS    6
#define QPB     8      // queries (rows) per block in the fused kernel

typedef unsigned long long u64;

// ---------------- workspace layout (bytes), total ~1.7 MB ----------------
#define OFF_RANGES 0
#define OFF_S      256
#define OFF_H      (OFF_S  + NPT*SDIM*4)

// key = (float_bits(d2) << 32) | j : u64 order == lex (d2, idx) order, which is
// exactly jax.lax.top_k's tie-breaking. d2 >= 0 so float bits are monotone.
#define INITK ((((u64)0x7f7fffffu) << 32) | 0xffffffffu)

__device__ __forceinline__ void ce(u64& a, u64& b) {   // a=min, b=max
    bool lt = a < b;
    u64 mn = lt ? a : b;
    u64 mx = lt ? b : a;
    a = mn; b = mx;
}
__device__ __forceinline__ u64 umin64(u64 a, u64 b) { return a < b ? a : b; }

__device__ __forceinline__ void key_insert(u64 key, u64* u) {
#pragma unroll
    for (int t = 0; t < KNN; ++t) {
        bool lt = key < u[t];
        u64 mn = lt ? key  : u[t];
        u64 mx = lt ? u[t] : key;
        u[t] = mn;
        key  = mx;
    }
}

// match reference numerics: rounded squares, sequential sum, no fma
__device__ __forceinline__ float dist2(const float4 a, const float4 b) {
    float d0 = a.x - b.x;
    float d1 = a.y - b.y;
    float d2 = a.z - b.z;
    float d3 = a.w - b.w;
    return __fadd_rn(__fadd_rn(__fadd_rn(__fmul_rn(d0, d0),
                                         __fmul_rn(d1, d1)),
                               __fmul_rn(d2, d2)),
                     __fmul_rn(d3, d3));
}

// 12-CE bitonic sort of a bitonic 8-sequence (m0..m7), ascending result
#define BITONIC8(m0,m1,m2,m3,m4,m5,m6,m7) \
    ce(m0,m4); ce(m1,m5); ce(m2,m6); ce(m3,m7); \
    ce(m0,m2); ce(m1,m3); ce(m4,m6); ce(m5,m7); \
    ce(m0,m1); ce(m2,m3); ce(m4,m5); ce(m6,m7);

// ---------------------------------------------------------
// s = (x@Ws + bs) + 1000*batch ; h = x@Wh + bh  (conv index 1 weights).
// Thread = (row i, slot o): o<4 -> S, o<26 -> H, o==31 -> graph ranges.
__global__ __launch_bounds__(256) void k_sh(const float* __restrict__ x,
                                            const int* __restrict__ batch,
                                            const float* __restrict__ Ws,
                                            const float* __restrict__ bs,
                                            const float* __restrict__ Wh,
                                            const float* __restrict__ bh,
                                            float* __restrict__ S,
                                            float* __restrict__ H,
                                            int* __restrict__ ranges) {
    int t = blockIdx.x * blockDim.x + threadIdx.x;
    int i = t >> 5;
    int o = t & 31;
    if (i >= NPT) return;
    if (o == 31) {  // graph ranges from sorted batch
        int b = batch[i];
        if (i == 0 || batch[i - 1] != b) ranges[b * 2]     = i;
        if (i == NPT - 1 || batch[i + 1] != b) ranges[b * 2 + 1] = i + 1;
        return;
    }
    const float* xr = x + (size_t)i * IN_F;
    if (o < SDIM) {
        float acc = 0.f;
        for (int k = 0; k < IN_F; ++k) acc += xr[k] * Ws[k * SDIM + o];
        S[(size_t)i * SDIM + o] = (acc + bs[o]) + 1000.f * (float)batch[i];
    } else if (o < SDIM + PDIM) {
        int p = o - SDIM;
        float acc = 0.f;
        for (int k = 0; k < IN_F; ++k) acc += xr[k] * Wh[k * PDIM + p];
        H[(size_t)i * PDIM + p] = acc + bh[p];
    }
}

// Fused kNN + gather + MLP. Block = 8 queries x 32 lanes.
// Phase A: round-7 butterfly kNN (u64 keys, batch-4 sorting networks) --
//   results stay in LDS, no global KIDX/KW round-trip.
// Phase B: gather/aggregate, et, h1, h2 (W2 LDS-staged, 128-padded,
//   conflict-light), out folded in-register with a shfl butterfly reduce.
// Rationale (round-9 PMC): k_fused alone ran at 110 GB/s = FETCH/dur --
//   duration WAS the cold-miss latency (x/H scattered across XCD L2s, no
//   work to hide it). Fusing puts ~20us of kNN VALU work in the same
//   kernel, so other blocks' phase-A hides phase-B's misses.
__global__ __launch_bounds__(256, 4) void k_knnmlp(
        const float4* __restrict__ S4,
        const int* __restrict__ batch,
        const int* __restrict__ ranges,
        const float* __restrict__ x,
        const float* __restrict__ H,
        const float* __restrict__ Wo1,
        const float* __restrict__ Wo2,
        const float* __restrict__ bo2,
        const float* __restrict__ W1,
        const float* __restrict__ b1,
        const float* __restrict__ W2,
        const float* __restrict__ b2,
        const float* __restrict__ W3,
        const float* __restrict__ b3,
        float* __restrict__ out) {
    __shared__ float xt[QPB * IN_F];        // 8x34
    __shared__ int   kidx_l[QPB * KNN];     // 8x8
    __shared__ float kw_l[QPB * KNN];       // 8x8
    __shared__ float aggt[QPB * 2 * PDIM];  // 8x44
    __shared__ float et[QPB * IN_F];        // 8x34
    __shared__ float h1t[QPB * WPAD];       // 8x128 (cols 126/127 = 0)
    __shared__ float wbuf[IN_F * WPAD];     // 34x128: W1, then W2 chunks
    __shared__ float w3buf[WPAD * NCLS];    // 128x6, rows 126/127 = 0
                                            // total = 28672 B -> 5 blocks/CU

    const int tid  = threadIdx.x;
    const int r    = tid >> 5;              // query-group / row 0..7
    const int c    = tid & 31;              // lane in group
    const int q    = blockIdx.x * QPB + r;  // this group's query/row
    const int row0 = blockIdx.x * QPB;

    // ---- issue long-latency staging NOW; drains under phase A ----
    for (int t = tid; t < QPB * IN_F; t += 256)
        xt[t] = x[(size_t)row0 * IN_F + t];
    for (int t = tid; t < IN_F * WPAD; t += 256) {
        int k = t >> 7, j = t & 127;
        wbuf[t] = (j < WIDTH) ? W1[k * WIDTH + j] : 0.f;
    }
    for (int t = tid; t < WPAD * NCLS; t += 256) {
        int k = t / NCLS;
        w3buf[t] = (k < WIDTH) ? W3[t] : 0.f;
    }

    // ================= Phase A: kNN =================
    {
        const int b   = batch[q];
        const int gs  = ranges[b * 2];
        const int len = ranges[b * 2 + 1] - gs;
        const float4 sq = S4[q];

        u64 u[KNN];
#pragma unroll
        for (int e = 0; e < KNN; ++e) u[e] = INITK;

        const int nfull = len >> 7;     // full 128-candidate (4/lane) batches
        int j = gs + c;
        for (int bb = 0; bb < nfull; ++bb, j += 128) {
            const float4* p = S4 + j;
            float4 s0 = p[0];
            float4 s1 = p[32];
            float4 s2 = p[64];
            float4 s3 = p[96];
            u64 k0 = ((u64)__float_as_uint(dist2(sq, s0)) << 32) | (unsigned)(j);
            u64 k1 = ((u64)__float_as_uint(dist2(sq, s1)) << 32) | (unsigned)(j + 32);
            u64 k2 = ((u64)__float_as_uint(dist2(sq, s2)) << 32) | (unsigned)(j + 64);
            u64 k3 = ((u64)__float_as_uint(dist2(sq, s3)) << 32) | (unsigned)(j + 96);
            ce(k0, k1); ce(k2, k3); ce(k0, k2); ce(k1, k3); ce(k1, k2);
            u64 m0 = umin64(k0, u[7]);
            u64 m1 = umin64(k1, u[6]);
            u64 m2 = umin64(k2, u[5]);
            u64 m3 = umin64(k3, u[4]);
            u64 m4 = u[3], m5 = u[2], m6 = u[1], m7 = u[0];
            BITONIC8(m0, m1, m2, m3, m4, m5, m6, m7);
            u[0] = m0; u[1] = m1; u[2] = m2; u[3] = m3;
            u[4] = m4; u[5] = m5; u[6] = m6; u[7] = m7;
        }
        for (int m = (nfull << 7) + c; m < len; m += 32) {
            int jj = gs + m;
            key_insert(((u64)__float_as_uint(dist2(sq, S4[jj])) << 32) | (unsigned)jj, u);
        }
#pragma unroll
        for (int mm = 1; mm < 32; mm <<= 1) {
            u64 p0 = (u64)__shfl_xor((long long)u[0], mm, 32);
            u64 p1 = (u64)__shfl_xor((long long)u[1], mm, 32);
            u64 p2 = (u64)__shfl_xor((long long)u[2], mm, 32);
            u64 p3 = (u64)__shfl_xor((long long)u[3], mm, 32);
            u64 p4 = (u64)__shfl_xor((long long)u[4], mm, 32);
            u64 p5 = (u64)__shfl_xor((long long)u[5], mm, 32);
            u64 p6 = (u64)__shfl_xor((long long)u[6], mm, 32);
            u64 p7 = (u64)__shfl_xor((long long)u[7], mm, 32);
            u64 m0 = umin64(u[0], p7);
            u64 m1 = umin64(u[1], p6);
            u64 m2 = umin64(u[2], p5);
            u64 m3 = umin64(u[3], p4);
            u64 m4 = umin64(u[4], p3);
            u64 m5 = umin64(u[5], p2);
            u64 m6 = umin64(u[6], p1);
            u64 m7 = umin64(u[7], p0);
            BITONIC8(m0, m1, m2, m3, m4, m5, m6, m7);
            u[0] = m0; u[1] = m1; u[2] = m2; u[3] = m3;
            u[4] = m4; u[5] = m5; u[6] = m6; u[7] = m7;
        }
        // all 32 lanes hold the identical merged list; lanes 0..7 publish
        if (c < KNN) {
            u64 ue = u[c];
            float d = __uint_as_float((unsigned)(ue >> 32));
            kidx_l[r * KNN + c] = (int)(unsigned)(ue & 0xffffffffu);
            kw_l[r * KNN + c]   = expf(-10.f * d);
        }
    }
    __syncthreads();

    // ================= Phase B: gather + MLP =================
    // gather + aggregate: lane c<22 owns dim c of row r
    if (c < PDIM) {
        float s = 0.f, mx = -FLT_MAX;
#pragma unroll
        for (int k = 0; k < KNN; ++k) {
            int   j = kidx_l[r * KNN + k];
            float w = kw_l[r * KNN + k];
            float v = H[(size_t)j * PDIM + c] * w;
            s += v; mx = fmaxf(mx, v);
        }
        aggt[r * 44 + c]        = s * 0.125f;
        aggt[r * 44 + PDIM + c] = mx;
    }
    __syncthreads();

    // et = x@Wo1 + agg@Wo2 + bo2 : lane c owns outs {c, 32+c(<34)}
    {
        float a0 = 0.f, a1 = 0.f;
        const float* ar = xt + r * IN_F;
        const bool two = (32 + c < IN_F);
#pragma unroll 4
        for (int k = 0; k < IN_F; ++k) {
            float av = ar[k];
            a0 += av * Wo1[k * IN_F + c];
            if (two) a1 += av * Wo1[k * IN_F + 32 + c];
        }
        const float* gr = aggt + r * 44;
#pragma unroll 4
        for (int p = 0; p < 2 * PDIM; ++p) {
            float av = gr[p];
            a0 += av * Wo2[p * IN_F + c];
            if (two) a1 += av * Wo2[p * IN_F + 32 + c];
        }
        et[r * IN_F + c] = a0 + bo2[c];
        if (two) et[r * IN_F + 32 + c] = a1 + bo2[32 + c];
    }
    __syncthreads();

    // h1 = elu(et@W1 + b1): lane c owns outs 4c..4c+3 (126/127 padded -> 0)
    {
        float acc[4] = {0.f, 0.f, 0.f, 0.f};
        const float* ar = et + r * IN_F;
#pragma unroll 4
        for (int k = 0; k < IN_F; ++k) {
            float av = ar[k];
            const float4 w4 = *(const float4*)(wbuf + k * WPAD + 4 * c);
            acc[0] += av * w4.x; acc[1] += av * w4.y;
            acc[2] += av * w4.z; acc[3] += av * w4.w;
        }
#pragma unroll
        for (int jj = 0; jj < 4; ++jj) {
            int j = 4 * c + jj;
            float v = acc[jj] + b1[j < WIDTH ? j : WIDTH - 1];
            h1t[r * WPAD + j] = (j < WIDTH) ? (v > 0.f ? v : expm1f(v)) : 0.f;
        }
    }
    __syncthreads();

    // h2 accumulation (W2 staged in 4 uniform 32-row chunks), out folded
    {
        float acc[4] = {0.f, 0.f, 0.f, 0.f};
        const float* ar = h1t + r * WPAD;
#pragma unroll 1
        for (int ck = 0; ck < 4; ++ck) {
            const int k0 = ck * 32;
            for (int t = tid; t < 32 * WPAD; t += 256) {
                int kk = t >> 7, j = t & 127;
                int row = k0 + kk;
                wbuf[t] = (j < WIDTH && row < WIDTH) ? W2[(size_t)row * WIDTH + j] : 0.f;
            }
            __syncthreads();
#pragma unroll 4
            for (int k = 0; k < 32; ++k) {
                float av = ar[k0 + k];
                const float4 w4 = *(const float4*)(wbuf + k * WPAD + 4 * c);
                acc[0] += av * w4.x; acc[1] += av * w4.y;
                acc[2] += av * w4.z; acc[3] += av * w4.w;
            }
            __syncthreads();
        }
        // h2 = elu(acc+b2) in-register; partial out = h2 * W3 rows 4c..4c+3
        float pc[NCLS] = {0.f, 0.f, 0.f, 0.f, 0.f, 0.f};
#pragma unroll
        for (int jj = 0; jj < 4; ++jj) {
            int j = 4 * c + jj;
            float v = acc[jj] + b2[j < WIDTH ? j : WIDTH - 1];
            float h2v = (j < WIDTH) ? (v > 0.f ? v : expm1f(v)) : 0.f;
            const float* w3r = w3buf + j * NCLS;   // zero rows for j>=126
#pragma unroll
            for (int cc = 0; cc < NCLS; ++cc) pc[cc] += h2v * w3r[cc];
        }
        // reduce the 32 lanes' partials
#pragma unroll
        for (int mm = 1; mm < 32; mm <<= 1) {
#pragma unroll
            for (int cc = 0; cc < NCLS; ++cc)
                pc[cc] += __shfl_xor(pc[cc], mm, 32);
        }
        if (c == 0) {
#pragma unroll
            for (int cc = 0; cc < NCLS; ++cc)
                out[(size_t)q * NCLS + cc] = pc[cc] + b3[cc];
        }
    }
}

extern "C" void kernel_launch(void* const* d_in, const int* in_sizes, int n_in,
                              void* d_out, int out_size, void* d_ws, size_t ws_size,
                              hipStream_t stream) {
    const float* x     = (const float*)d_in[0];
    const int*   batch = (const int*)d_in[1];
    // Only conv index NCONV-1 == 1 affects the output (loop discards earlier)
    const float* Ws  = (const float*)d_in[2] + IN_F * SDIM;
    const float* bs  = (const float*)d_in[3] + SDIM;
    const float* Wh  = (const float*)d_in[4] + IN_F * PDIM;
    const float* bh  = (const float*)d_in[5] + PDIM;
    const float* Wo1 = (const float*)d_in[6] + IN_F * IN_F;
    const float* Wo2 = (const float*)d_in[7] + 2 * PDIM * IN_F;
    const float* bo2 = (const float*)d_in[8] + IN_F;
    const float* W1  = (const float*)d_in[9];
    const float* b1  = (const float*)d_in[10];
    const float* W2  = (const float*)d_in[11];
    const float* b2  = (const float*)d_in[12];
    const float* W3  = (const float*)d_in[13];
    const float* b3  = (const float*)d_in[14];
    float* out = (float*)d_out;

    char* ws = (char*)d_ws;
    int*   ranges = (int*)(ws + OFF_RANGES);
    float* S      = (float*)(ws + OFF_S);
    float* H      = (float*)(ws + OFF_H);

    k_sh<<<dim3(NPT * 32 / 256), dim3(256), 0, stream>>>(x, batch, Ws, bs, Wh, bh, S, H, ranges);
    k_knnmlp<<<dim3(NPT / QPB), dim3(256), 0, stream>>>((const float4*)S, batch, ranges,
                                                        x, H, Wo1, Wo2, bo2,
                                                        W1, b1, W2, b2, W3, b3, out);
}

// Round 11
// 97.592 us; speedup vs baseline: 1.1714x; 1.1714x over previous
//
#include <hip/hip_runtime.h>
#include <math.h>
#include <float.h>

// Problem constants (from reference)
#define NPT     16384
#define IN_F    34
#define SDIM    4
#define PDIM    22
#define KNN     8
#define WIDTH   126
#define WPAD    128    // padded width for conflict-free LDS
#define NCLS    6
#define ROWS    32     // rows per fused-MLP block (512 threads, 16 lanes/row)

typedef unsigned long long u64;

// ---------------- workspace layout (bytes), total ~3 MB ----------------
#define OFF_RANGES 0
#define OFF_S      256
#define OFF_H      (OFF_S  + NPT*SDIM*4)
#define OFF_KIDX   (OFF_H  + NPT*PDIM*4)
#define OFF_KW     (OFF_KIDX + NPT*KNN*4)

// key = (float_bits(d2) << 32) | j : u64 order == lex (d2, idx) order, which is
// exactly jax.lax.top_k's tie-breaking. d2 >= 0 so float bits are monotone.
#define INITK ((((u64)0x7f7fffffu) << 32) | 0xffffffffu)

__device__ __forceinline__ void ce(u64& a, u64& b) {   // a=min, b=max
    bool lt = a < b;
    u64 mn = lt ? a : b;
    u64 mx = lt ? b : a;
    a = mn; b = mx;
}
__device__ __forceinline__ u64 umin64(u64 a, u64 b) { return a < b ? a : b; }

__device__ __forceinline__ void key_insert(u64 key, u64* u) {
#pragma unroll
    for (int t = 0; t < KNN; ++t) {
        bool lt = key < u[t];
        u64 mn = lt ? key  : u[t];
        u64 mx = lt ? u[t] : key;
        u[t] = mn;
        key  = mx;
    }
}

// match reference numerics: rounded squares, sequential sum, no fma
__device__ __forceinline__ float dist2(const float4 a, const float4 b) {
    float d0 = a.x - b.x;
    float d1 = a.y - b.y;
    float d2 = a.z - b.z;
    float d3 = a.w - b.w;
    return __fadd_rn(__fadd_rn(__fadd_rn(__fmul_rn(d0, d0),
                                         __fmul_rn(d1, d1)),
                               __fmul_rn(d2, d2)),
                     __fmul_rn(d3, d3));
}

// 12-CE bitonic sort of a bitonic 8-sequence (m0..m7), ascending result
#define BITONIC8(m0,m1,m2,m3,m4,m5,m6,m7) \
    ce(m0,m4); ce(m1,m5); ce(m2,m6); ce(m3,m7); \
    ce(m0,m2); ce(m1,m3); ce(m4,m6); ce(m5,m7); \
    ce(m0,m1); ce(m2,m3); ce(m4,m5); ce(m6,m7);

// ---------------------------------------------------------
// s = (x@Ws + bs) + 1000*batch ; h = x@Wh + bh  (conv index 1 weights).
// Thread = (row i, slot o): o<4 -> S, o<26 -> H, o==31 -> graph ranges.
__global__ __launch_bounds__(256) void k_sh(const float* __restrict__ x,
                                            const int* __restrict__ batch,
                                            const float* __restrict__ Ws,
                                            const float* __restrict__ bs,
                                            const float* __restrict__ Wh,
                                            const float* __restrict__ bh,
                                            float* __restrict__ S,
                                            float* __restrict__ H,
                                            int* __restrict__ ranges) {
    int t = blockIdx.x * blockDim.x + threadIdx.x;
    int i = t >> 5;
    int o = t & 31;
    if (i >= NPT) return;
    if (o == 31) {  // graph ranges from sorted batch
        int b = batch[i];
        if (i == 0 || batch[i - 1] != b) ranges[b * 2]     = i;
        if (i == NPT - 1 || batch[i + 1] != b) ranges[b * 2 + 1] = i + 1;
        return;
    }
    const float* xr = x + (size_t)i * IN_F;
    if (o < SDIM) {
        float acc = 0.f;
        for (int k = 0; k < IN_F; ++k) acc += xr[k] * Ws[k * SDIM + o];
        S[(size_t)i * SDIM + o] = (acc + bs[o]) + 1000.f * (float)batch[i];
    } else if (o < SDIM + PDIM) {
        int p = o - SDIM;
        float acc = 0.f;
        for (int k = 0; k < IN_F; ++k) acc += xr[k] * Wh[k * PDIM + p];
        H[(size_t)i * PDIM + p] = acc + bh[p];
    }
}

// Fused kNN: 32 lanes per query, interleaved candidates, batch-4 sorting
// networks + butterfly merge of sorted-8 lists (round 7; exact u64 order).
__global__ __launch_bounds__(256, 4) void k_knn(const float4* __restrict__ S4,
                                                const int* __restrict__ batch,
                                                const int* __restrict__ ranges,
                                                int* __restrict__ KIDX,
                                                float* __restrict__ KW) {
    const int tid = threadIdx.x;
    const int q   = blockIdx.x * 8 + (tid >> 5);
    const int t   = tid & 31;
    const int b   = batch[q];
    const int gs  = ranges[b * 2];
    const int len = ranges[b * 2 + 1] - gs;
    const float4 sq = S4[q];

    u64 u[KNN];
#pragma unroll
    for (int e = 0; e < KNN; ++e) u[e] = INITK;

    const int nfull = len >> 7;     // full 128-candidate (4/lane) batches
    int j = gs + t;
    for (int bb = 0; bb < nfull; ++bb, j += 128) {
        const float4* p = S4 + j;
        float4 s0 = p[0];
        float4 s1 = p[32];
        float4 s2 = p[64];
        float4 s3 = p[96];
        u64 k0 = ((u64)__float_as_uint(dist2(sq, s0)) << 32) | (unsigned)(j);
        u64 k1 = ((u64)__float_as_uint(dist2(sq, s1)) << 32) | (unsigned)(j + 32);
        u64 k2 = ((u64)__float_as_uint(dist2(sq, s2)) << 32) | (unsigned)(j + 64);
        u64 k3 = ((u64)__float_as_uint(dist2(sq, s3)) << 32) | (unsigned)(j + 96);
        // sort 4
        ce(k0, k1); ce(k2, k3); ce(k0, k2); ce(k1, k3); ce(k1, k2);
        // half-cleaner vs sorted u (k padded with +inf -> those slots pass u through)
        u64 m0 = umin64(k0, u[7]);
        u64 m1 = umin64(k1, u[6]);
        u64 m2 = umin64(k2, u[5]);
        u64 m3 = umin64(k3, u[4]);
        u64 m4 = u[3], m5 = u[2], m6 = u[1], m7 = u[0];
        BITONIC8(m0, m1, m2, m3, m4, m5, m6, m7);
        u[0] = m0; u[1] = m1; u[2] = m2; u[3] = m3;
        u[4] = m4; u[5] = m5; u[6] = m6; u[7] = m7;
    }
    // tail: per-lane <=4 singleton inserts (exact; order irrelevant)
    for (int m = (nfull << 7) + t; m < len; m += 32) {
        int jj = gs + m;
        key_insert(((u64)__float_as_uint(dist2(sq, S4[jj])) << 32) | (unsigned)jj, u);
    }

    // butterfly across the 32-lane group: merge two sorted-8 lists per step
#pragma unroll
    for (int mm = 1; mm < 32; mm <<= 1) {
        u64 p0 = (u64)__shfl_xor((long long)u[0], mm, 32);
        u64 p1 = (u64)__shfl_xor((long long)u[1], mm, 32);
        u64 p2 = (u64)__shfl_xor((long long)u[2], mm, 32);
        u64 p3 = (u64)__shfl_xor((long long)u[3], mm, 32);
        u64 p4 = (u64)__shfl_xor((long long)u[4], mm, 32);
        u64 p5 = (u64)__shfl_xor((long long)u[5], mm, 32);
        u64 p6 = (u64)__shfl_xor((long long)u[6], mm, 32);
        u64 p7 = (u64)__shfl_xor((long long)u[7], mm, 32);
        u64 m0 = umin64(u[0], p7);
        u64 m1 = umin64(u[1], p6);
        u64 m2 = umin64(u[2], p5);
        u64 m3 = umin64(u[3], p4);
        u64 m4 = umin64(u[4], p3);
        u64 m5 = umin64(u[5], p2);
        u64 m6 = umin64(u[6], p1);
        u64 m7 = umin64(u[7], p0);
        BITONIC8(m0, m1, m2, m3, m4, m5, m6, m7);
        u[0] = m0; u[1] = m1; u[2] = m2; u[3] = m3;
        u[4] = m4; u[5] = m5; u[6] = m6; u[7] = m7;
    }

    if (t == 0) {
#pragma unroll
        for (int e = 0; e < KNN; ++e) {
            float d = __uint_as_float((unsigned)(u[e] >> 32));
            KIDX[(size_t)q * KNN + e] = (int)(unsigned)(u[e] & 0xffffffffu);
            KW[(size_t)q * KNN + e]   = expf(-10.f * d);
        }
    }
}

// Fused gather+MLP, round-11 rebuild:
//  - ROWS=32 @ 512 threads -> grid 512 = exactly 2 resident blocks/CU (one
//    block-round, W2 staged once per 32 rows instead of per 16).
//  - W2 double-buffered + register-staged: chunk k+1's loads are issued
//    before chunk k's compute and drain under it; ONE barrier per chunk.
//    (Round-9's stage/sync/compute/sync serialization was the 63us culprit:
//    dur == FETCH/110GB/s, pure latency.)
//  - chunk0 loads issued before the et phase (~2000cy extra overlap).
//  - h2 -> out folded in-register (width-16 shfl reduce); h2t deleted.
__global__ __launch_bounds__(512, 4) void k_fused(
        const float* __restrict__ x,
        const float* __restrict__ H,
        const int* __restrict__ KIDX,
        const float* __restrict__ KW,
        const float* __restrict__ Wo1,
        const float* __restrict__ Wo2,
        const float* __restrict__ bo2,
        const float* __restrict__ W1,
        const float* __restrict__ b1,
        const float* __restrict__ W2,
        const float* __restrict__ b2,
        const float* __restrict__ W3,
        const float* __restrict__ b3,
        float* __restrict__ out) {
    __shared__ float xt[ROWS * IN_F];       // 32x34
    __shared__ float aggt[ROWS * 2 * PDIM]; // 32x44
    __shared__ float et[ROWS * IN_F];       // 32x34
    __shared__ float h1t[ROWS * WPAD];      // 32x128 (cols 126/127 = 0)
    __shared__ float wbuf[2 * 32 * WPAD];   // 2 x 32x128: W1 (34 rows split
                                            // [0]=rows0-31,[1]=rows32-33), then
                                            // W2 double-buffer. 32 KB.
    __shared__ float w3buf[WPAD * NCLS];    // 128x6, rows 126/127 = 0
                                            // total = 66560 B -> 2 blocks/CU

    const int tid  = threadIdx.x;
    const int r    = tid >> 4;              // row 0..31
    const int c    = tid & 15;              // lane-in-row 0..15
    const int row0 = blockIdx.x * ROWS;
    const int gi   = row0 + r;
    const int jA   = 4 * c;                 // cols 0..63
    const int jB   = 64 + 4 * c;            // cols 64..127 (126/127 pad)

    // ---- staging: x, W1 (rows split over both wbuf halves), W3 ----
    for (int t = tid; t < ROWS * IN_F; t += 512)
        xt[t] = x[(size_t)row0 * IN_F + t];
    for (int t = tid; t < IN_F * WPAD; t += 512) {
        int k = t >> 7, j = t & 127;
        wbuf[(k >> 5) * (32 * WPAD) + (k & 31) * WPAD + j] =
            (j < WIDTH) ? W1[k * WIDTH + j] : 0.f;
    }
    for (int t = tid; t < WPAD * NCLS; t += 512) {
        int k = t / NCLS;
        w3buf[t] = (k < WIDTH) ? W3[t] : 0.f;
    }

    // gather + aggregate: lane c<11 handles dims {c, c+11}
    if (c < 11) {
        const int p0 = c, p1 = c + 11;
        float s0 = 0.f, s1 = 0.f;
        float m0 = -FLT_MAX, m1 = -FLT_MAX;
#pragma unroll
        for (int k = 0; k < KNN; ++k) {
            int   j = KIDX[(size_t)gi * KNN + k];
            float w = KW[(size_t)gi * KNN + k];
            const float* hr = H + (size_t)j * PDIM;
            float v0 = hr[p0] * w; s0 += v0; m0 = fmaxf(m0, v0);
            float v1 = hr[p1] * w; s1 += v1; m1 = fmaxf(m1, v1);
        }
        aggt[r * 44 + p0] = s0 * 0.125f; aggt[r * 44 + PDIM + p0] = m0;
        aggt[r * 44 + p1] = s1 * 0.125f; aggt[r * 44 + PDIM + p1] = m1;
    }
    __syncthreads();   // xt, W1, w3, aggt all visible

    // issue W2 chunk0 loads NOW; they drain under et + h1 compute.
    // element e = i*512+tid -> kk=e>>7, j=e&127 : coalesced rows, and the
    // later LDS store (lane-consecutive e) is bank-conflict-free.
    float rvA[8], rvB[8];
#pragma unroll
    for (int i = 0; i < 8; ++i) {
        int e = i * 512 + tid, kk = e >> 7, j = e & 127;
        rvA[i] = (j < WIDTH) ? W2[(size_t)kk * WIDTH + j] : 0.f;  // rows 0..31
    }

    // et = x@Wo1 + agg@Wo2 + bo2 ; 3-wide chunks, j0=min(3c,31); overlap
    // lanes write bitwise-identical duplicates (benign); Wo1/Wo2 L1/L2-hot
    {
        const int j0 = (3 * c < 31) ? 3 * c : 31;
        float acc[3] = {0.f, 0.f, 0.f};
        const float* ar = xt + r * IN_F;
#pragma unroll 4
        for (int k = 0; k < IN_F; ++k) {
            float av = ar[k];
            const float* wr = Wo1 + k * IN_F + j0;
#pragma unroll
            for (int jj = 0; jj < 3; ++jj) acc[jj] += av * wr[jj];
        }
        const float* gr = aggt + r * 44;
#pragma unroll 4
        for (int p = 0; p < 2 * PDIM; ++p) {
            float av = gr[p];
            const float* wr = Wo2 + p * IN_F + j0;
#pragma unroll
            for (int jj = 0; jj < 3; ++jj) acc[jj] += av * wr[jj];
        }
#pragma unroll
        for (int jj = 0; jj < 3; ++jj)
            et[r * IN_F + j0 + jj] = acc[jj] + bo2[j0 + jj];
    }
    __syncthreads();   // et ready

    // h1 = elu(et@W1 + b1), W1 from LDS (rows k: half k>>5, row k&31)
    {
        float aA[4] = {0.f, 0.f, 0.f, 0.f};
        float aB[4] = {0.f, 0.f, 0.f, 0.f};
        const float* ar = et + r * IN_F;
#pragma unroll 4
        for (int k = 0; k < IN_F; ++k) {
            float av = ar[k];
            const float* wr = wbuf + (k >> 5) * (32 * WPAD) + (k & 31) * WPAD;
            const float4 wA = *(const float4*)(wr + jA);
            const float4 wB = *(const float4*)(wr + jB);
            aA[0] += av * wA.x; aA[1] += av * wA.y;
            aA[2] += av * wA.z; aA[3] += av * wA.w;
            aB[0] += av * wB.x; aB[1] += av * wB.y;
            aB[2] += av * wB.z; aB[3] += av * wB.w;
        }
#pragma unroll
        for (int jj = 0; jj < 4; ++jj) {
            float vA = aA[jj] + b1[jA + jj];
            h1t[r * WPAD + jA + jj] = vA > 0.f ? vA : expm1f(vA);
            int j = jB + jj;
            float vB = aB[jj] + b1[j < WIDTH ? j : WIDTH - 1];
            h1t[r * WPAD + j] = (j < WIDTH) ? (vB > 0.f ? vB : expm1f(vB)) : 0.f;
        }
    }
    __syncthreads();   // h1t ready; ALL W1 reads done -> wbuf reusable

    // ---- h2 with double-buffered W2 (one barrier per chunk) ----
    float aA[4] = {0.f, 0.f, 0.f, 0.f};
    float aB[4] = {0.f, 0.f, 0.f, 0.f};
    const float* ar = h1t + r * WPAD;

#define STORE_CHUNK(BUFI, RV)                                   \
    _Pragma("unroll")                                           \
    for (int i = 0; i < 8; ++i)                                 \
        wbuf[(BUFI) * 4096 + i * 512 + tid] = RV[i];

#define LOAD_CHUNK(RV, K0)                                      \
    _Pragma("unroll")                                           \
    for (int i = 0; i < 8; ++i) {                               \
        int e = i * 512 + tid, kk = e >> 7, j = e & 127;        \
        int row = (K0) + kk;                                    \
        RV[i] = (j < WIDTH && row < WIDTH)                      \
                    ? W2[(size_t)row * WIDTH + j] : 0.f;        \
    }

#define COMPUTE_CHUNK(BUFI, K0)                                 \
    {                                                           \
        const float* wb = wbuf + (BUFI) * 4096;                 \
        _Pragma("unroll 4")                                     \
        for (int k = 0; k < 32; ++k) {                          \
            float av = ar[(K0) + k];                            \
            const float4 wA = *(const float4*)(wb + k * WPAD + jA); \
            const float4 wB = *(const float4*)(wb + k * WPAD + jB); \
            aA[0] += av * wA.x; aA[1] += av * wA.y;             \
            aA[2] += av * wA.z; aA[3] += av * wA.w;             \
            aB[0] += av * wB.x; aB[1] += av * wB.y;             \
            aB[2] += av * wB.z; aB[3] += av * wB.w;             \
        }                                                       \
    }

    STORE_CHUNK(0, rvA);  LOAD_CHUNK(rvB, 32);
    __syncthreads();
    COMPUTE_CHUNK(0, 0);
    STORE_CHUNK(1, rvB);  LOAD_CHUNK(rvA, 64);
    __syncthreads();
    COMPUTE_CHUNK(1, 32);
    STORE_CHUNK(0, rvA);  LOAD_CHUNK(rvB, 96);
    __syncthreads();
    COMPUTE_CHUNK(0, 64);
    STORE_CHUNK(1, rvB);
    __syncthreads();
    COMPUTE_CHUNK(1, 96);

    // h2 = elu(acc+b2) in-register; fold out = h2@W3 (w3buf rows pad 0)
    {
        float pc[NCLS] = {0.f, 0.f, 0.f, 0.f, 0.f, 0.f};
#pragma unroll
        for (int jj = 0; jj < 4; ++jj) {
            int ja = jA + jj;
            float vA = aA[jj] + b2[ja];
            float hA = vA > 0.f ? vA : expm1f(vA);
            const float* w3a = w3buf + ja * NCLS;
#pragma unroll
            for (int cc = 0; cc < NCLS; ++cc) pc[cc] += hA * w3a[cc];
            int jb = jB + jj;
            float vB = aB[jj] + b2[jb < WIDTH ? jb : WIDTH - 1];
            float hB = (jb < WIDTH) ? (vB > 0.f ? vB : expm1f(vB)) : 0.f;
            const float* w3b = w3buf + jb * NCLS;
#pragma unroll
            for (int cc = 0; cc < NCLS; ++cc) pc[cc] += hB * w3b[cc];
        }
        // reduce across the 16 lanes of this row
#pragma unroll
        for (int mm = 1; mm < 16; mm <<= 1) {
#pragma unroll
            for (int cc = 0; cc < NCLS; ++cc)
                pc[cc] += __shfl_xor(pc[cc], mm, 16);
        }
        if (c == 0) {
#pragma unroll
            for (int cc = 0; cc < NCLS; ++cc)
                out[(size_t)gi * NCLS + cc] = pc[cc] + b3[cc];
        }
    }
#undef STORE_CHUNK
#undef LOAD_CHUNK
#undef COMPUTE_CHUNK
}

extern "C" void kernel_launch(void* const* d_in, const int* in_sizes, int n_in,
                              void* d_out, int out_size, void* d_ws, size_t ws_size,
                              hipStream_t stream) {
    const float* x     = (const float*)d_in[0];
    const int*   batch = (const int*)d_in[1];
    // Only conv index NCONV-1 == 1 affects the output (loop discards earlier)
    const float* Ws  = (const float*)d_in[2] + IN_F * SDIM;
    const float* bs  = (const float*)d_in[3] + SDIM;
    const float* Wh  = (const float*)d_in[4] + IN_F * PDIM;
    const float* bh  = (const float*)d_in[5] + PDIM;
    const float* Wo1 = (const float*)d_in[6] + IN_F * IN_F;
    const float* Wo2 = (const float*)d_in[7] + 2 * PDIM * IN_F;
    const float* bo2 = (const float*)d_in[8] + IN_F;
    const float* W1  = (const float*)d_in[9];
    const float* b1  = (const float*)d_in[10];
    const float* W2  = (const float*)d_in[11];
    const float* b2  = (const float*)d_in[12];
    const float* W3  = (const float*)d_in[13];
    const float* b3  = (const float*)d_in[14];
    float* out = (float*)d_out;

    char* ws = (char*)d_ws;
    int*   ranges = (int*)(ws + OFF_RANGES);
    float* S      = (float*)(ws + OFF_S);
    float* H      = (float*)(ws + OFF_H);
    int*   KIDX   = (int*)(ws + OFF_KIDX);
    float* KW     = (float*)(ws + OFF_KW);

    k_sh<<<dim3(NPT * 32 / 256), dim3(256), 0, stream>>>(x, batch, Ws, bs, Wh, bh, S, H, ranges);
    k_knn<<<dim3(NPT / 8), dim3(256), 0, stream>>>((const float4*)S, batch, ranges, KIDX, KW);
    k_fused<<<dim3(NPT / ROWS), dim3(512), 0, stream>>>(x, H, KIDX, KW, Wo1, Wo2, bo2,
                                                        W1, b1, W2, b2, W3, b3, out);
}